// Round 3
// baseline (407.059 us; speedup 1.0000x reference)
//
#include <hip/hip_runtime.h>
#include <hip/hip_bf16.h>

typedef unsigned short u16;
typedef __bf16 bf16x8 __attribute__((ext_vector_type(8)));
typedef float f32x4 __attribute__((ext_vector_type(4)));
typedef u16 u16x8 __attribute__((ext_vector_type(8)));

__device__ __forceinline__ u16 f2bf(float f) {
    __bf16 h = (__bf16)f;                 // RNE
    return __builtin_bit_cast(unsigned short, h);
}

__device__ __forceinline__ void gl_lds16(const u16* g, u16* l) {
    __builtin_amdgcn_global_load_lds(
        (const __attribute__((address_space(1))) void*)g,
        (__attribute__((address_space(3))) void*)l, 16, 0, 0);
}

// ---------------------------------------------------------------------------
// Kernel 1: ternary quantization (unchanged — correct, ~5 µs).
// wq[o][f][ci] bf16, K-order = f*256 + ci. alpha[o] fp32.
// ---------------------------------------------------------------------------
__global__ __launch_bounds__(256) void quant_kernel(
        const float* __restrict__ w, u16* __restrict__ wq,
        float* __restrict__ alpha) {
    int o = blockIdx.x;
    int t = threadIdx.x;          // t == ci
    const float* wo = w + (size_t)o * 2304;
    float v[9];
    double asum = 0.0;
    #pragma unroll
    for (int i = 0; i < 9; ++i) { v[i] = wo[t * 9 + i]; asum += fabs((double)v[i]); }
    #pragma unroll
    for (int off = 32; off > 0; off >>= 1) asum += __shfl_down(asum, off, 64);
    __shared__ double red[4];
    int wv = t >> 6, lane = t & 63;
    if (lane == 0) red[wv] = asum;
    __syncthreads();
    double delta = 0.7 * ((red[0] + red[1] + red[2] + red[3]) / 2304.0);

    double msum = 0.0; int cnt = 0;
    #pragma unroll
    for (int i = 0; i < 9; ++i) {
        double f = (double)v[i];
        float tv = 0.f;
        if (f > delta) tv = 1.f;
        else if (f < -delta) tv = -1.f;
        if (tv != 0.f) { msum += fabs(f); cnt++; }
        wq[(size_t)o * 2304 + i * 256 + t] = f2bf(tv);
    }
    #pragma unroll
    for (int off = 32; off > 0; off >>= 1) {
        msum += __shfl_down(msum, off, 64);
        cnt  += __shfl_down(cnt,  off, 64);
    }
    __shared__ double red2[4];
    __shared__ int    redc[4];
    if (lane == 0) { red2[wv] = msum; redc[wv] = cnt; }
    __syncthreads();
    if (t == 0) {
        double ms = red2[0] + red2[1] + red2[2] + red2[3];
        int c = redc[0] + redc[1] + redc[2] + redc[3];
        alpha[o] = (float)(ms / (double)(c > 0 ? c : 1));
    }
}

// ---------------------------------------------------------------------------
// Kernel 2a: zero the padded halo of Xp[img][cihi32][58][58][8].
// grid (32, 32), 256 threads; 228 border (hp,wl) positions per slab.
// ---------------------------------------------------------------------------
__global__ __launch_bounds__(256) void border_kernel(u16* __restrict__ xp) {
    int img = blockIdx.x, cihi = blockIdx.y, t = threadIdx.x;
    if (t >= 228) return;
    int hp, wl;
    if (t < 58)       { hp = 0;           wl = t; }
    else if (t < 116) { hp = 57;          wl = t - 58; }
    else if (t < 172) { hp = t - 116 + 1; wl = 0; }
    else              { hp = t - 172 + 1; wl = 57; }
    u16x8 z = {};
    *(u16x8*)(xp + (((size_t)(img * 32 + cihi) * 58 + hp) * 58 + wl) * 8) = z;
}

// ---------------------------------------------------------------------------
// Kernel 2b: pad/transpose interior, LDS-free streaming.
// x NCHW fp32 -> Xp[img][cihi32][hp58][wp58][cilo8] bf16.
// grid (32 img, 32 cihi, 14 hq), block (56, 4): thread = one (h, w);
// 8 coalesced dword loads (channel stride 3136), one 16 B u16x8 store.
// ---------------------------------------------------------------------------
__global__ __launch_bounds__(256) void pad_kernel(
        const float* __restrict__ x, u16* __restrict__ xp) {
    int img  = blockIdx.x;
    int cihi = blockIdx.y;
    int h    = blockIdx.z * 4 + threadIdx.y;
    int w    = threadIdx.x;
    const float* xb = x + ((size_t)img * 256 + cihi * 8) * 3136 + h * 56 + w;
    u16x8 v;
    #pragma unroll
    for (int j = 0; j < 8; ++j) v[j] = f2bf(xb[(size_t)j * 3136]);
    *(u16x8*)(xp + (((size_t)(img * 32 + cihi) * 58 + (h + 1)) * 58 + (w + 1)) * 8) = v;
}

// ---------------------------------------------------------------------------
// Kernel 3: implicit GEMM, faithful m97 structure. BK=64, single-buffered
// LDS [kseg8][row128][cilo8] per operand (16 KB each). Per chunk: stage
// (8 gl_lds16/wave, all addressing wave-uniform) -> barrier -> 32 MFMA +
// 16 ds_read_b128 per wave -> barrier. 36 chunks (K = 9 taps * 256 ch).
// ---------------------------------------------------------------------------
__global__ __launch_bounds__(256) void conv_gemm(
        const u16* __restrict__ Wq, const u16* __restrict__ Xp,
        const float* __restrict__ alpha, float* __restrict__ out) {
    __shared__ u16 lsA[8 * 128 * 8];   // 16 KB: [kseg][o_row][8ch]
    __shared__ u16 lsB[8 * 128 * 8];   // 16 KB: [kseg][sp_row][8ch]

    // XCD swizzle (kept from R2: FETCH 438 -> 47 MB). bid&7 = xcd owns a
    // contiguous nt range; both mt blocks of one nt land on the same xcd.
    int bid = blockIdx.x;
    int xcd = bid & 7, idx = bid >> 3;
    int mt = idx & 1;
    unsigned nt = (unsigned)(xcd * 98 + (idx >> 1));
    int o_base = mt * 128;
    unsigned sp_base = nt * 128u;

    int t = threadIdx.x;
    int lane = t & 63, wave = t >> 6;
    int wm = (wave >> 1) * 64, wn = (wave & 1) * 64;

    // per-lane staging bases (lane = row within a 64-row half)
    const u16* aB0 = Wq + (size_t)(o_base + lane) * 2304;        // rows 0..63
    const u16* aB1 = aB0 + (size_t)64 * 2304;                    // rows 64..127

    unsigned sp0 = sp_base + (unsigned)lane;
    unsigned sp1 = sp0 + 64u;
    unsigned img0 = sp0 / 3136u, rem0 = sp0 - img0 * 3136u;
    unsigned oh0 = rem0 / 56u,   ow0 = rem0 - oh0 * 56u;
    unsigned img1 = sp1 / 3136u, rem1 = sp1 - img1 * 3136u;
    unsigned oh1 = rem1 / 56u,   ow1 = rem1 - oh1 * 56u;
    const u16* bB0 = Xp + ((size_t)(img0 * 32) * 58 + oh0) * 58 * 8 + ow0 * 8;
    const u16* bB1 = Xp + ((size_t)(img1 * 32) * 58 + oh1) * 58 * 8 + ow1 * 8;

    // wave-uniform LDS staging destinations: ksegs s0=2*wave, s1=s0+1
    int s0 = wave * 2, s1 = s0 + 1;
    u16* dA00 = lsA + (s0 * 128) * 8;       // [s0][rows 0..63]
    u16* dA01 = lsA + (s0 * 128 + 64) * 8;  // [s0][rows 64..127]
    u16* dA10 = lsA + (s1 * 128) * 8;
    u16* dA11 = lsA + (s1 * 128 + 64) * 8;
    u16* dB00 = lsB + (s0 * 128) * 8;
    u16* dB01 = lsB + (s0 * 128 + 64) * 8;
    u16* dB10 = lsB + (s1 * 128) * 8;
    u16* dB11 = lsB + (s1 * 128 + 64) * 8;

    f32x4 acc[4][4] = {};
    int row16 = lane & 15, quad = lane >> 4;

    for (int kc = 0; kc < 36; ++kc) {
        // chunk kc covers k in [kc*64, kc*64+64): tap f = kc>>2 (uniform),
        // channels ci0 = (kc&3)*64, i.e. cihi = (kc&3)*8 + kseg.
        int f  = kc >> 2;
        int kh = f / 3, kw = f - kh * 3;
        int ci8 = (kc & 3) * 8;
        unsigned aoff = (unsigned)(kc * 64);
        unsigned bhw  = (unsigned)kh * 464u + (unsigned)kw * 8u;
        unsigned bo0  = (unsigned)(ci8 + s0) * 26912u + bhw;
        unsigned bo1  = (unsigned)(ci8 + s1) * 26912u + bhw;

        gl_lds16(aB0 + aoff + s0 * 8, dA00);
        gl_lds16(aB1 + aoff + s0 * 8, dA01);
        gl_lds16(aB0 + aoff + s1 * 8, dA10);
        gl_lds16(aB1 + aoff + s1 * 8, dA11);
        gl_lds16(bB0 + bo0, dB00);
        gl_lds16(bB1 + bo0, dB01);
        gl_lds16(bB0 + bo1, dB10);
        gl_lds16(bB1 + bo1, dB11);

        __syncthreads();   // drains vmcnt: staged data visible

        #pragma unroll
        for (int kk = 0; kk < 2; ++kk) {
            int ks = kk * 4 + quad;
            bf16x8 af[4], bfr[4];
            #pragma unroll
            for (int i = 0; i < 4; ++i)
                af[i] = *(const bf16x8*)&lsA[(ks * 128 + wm + i * 16 + row16) * 8];
            #pragma unroll
            for (int j = 0; j < 4; ++j)
                bfr[j] = *(const bf16x8*)&lsB[(ks * 128 + wn + j * 16 + row16) * 8];
            #pragma unroll
            for (int i = 0; i < 4; ++i)
                #pragma unroll
                for (int j = 0; j < 4; ++j)
                    acc[i][j] = __builtin_amdgcn_mfma_f32_16x16x32_bf16(
                                    af[i], bfr[j], acc[i][j], 0, 0, 0);
        }

        __syncthreads();   // all reads done before next chunk's staging
    }

    // epilogue: C/D layout col=lane&15 (sp), row=quad*4+reg (o)
    int col = lane & 15;
    float al[4][4];
    #pragma unroll
    for (int i = 0; i < 4; ++i)
        #pragma unroll
        for (int rg = 0; rg < 4; ++rg)
            al[i][rg] = alpha[o_base + wm + i * 16 + quad * 4 + rg];

    #pragma unroll
    for (int j = 0; j < 4; ++j) {
        unsigned sp = sp_base + (unsigned)(wn + j * 16 + col);
        unsigned img = sp / 3136u;
        unsigned spi = sp - img * 3136u;
        float* ob = out + (size_t)img * 256 * 3136 + spi;
        #pragma unroll
        for (int i = 0; i < 4; ++i) {
            int o = o_base + wm + i * 16 + quad * 4;
            #pragma unroll
            for (int rg = 0; rg < 4; ++rg)
                ob[(size_t)(o + rg) * 3136] = acc[i][j][rg] * al[i][rg];
        }
    }
}

// ---------------------------------------------------------------------------
extern "C" void kernel_launch(void* const* d_in, const int* in_sizes, int n_in,
                              void* d_out, int out_size, void* d_ws, size_t ws_size,
                              hipStream_t stream) {
    const float* x = (const float*)d_in[0];
    const float* w = (const float*)d_in[1];
    float* out = (float*)d_out;

    char* ws = (char*)d_ws;
    // xp: 32*32*58*58*8 bf16 = 55,115,776 B
    u16*   xp    = (u16*)ws;
    u16*   wq    = (u16*)(ws + 55115776);           // 256*2304 bf16
    float* alpha = (float*)(ws + 55115776 + 1179648);

    quant_kernel<<<256, 256, 0, stream>>>(w, wq, alpha);
    dim3 bg(32, 32);
    border_kernel<<<bg, 256, 0, stream>>>(xp);
    dim3 pg(32, 32, 14);
    dim3 pb(56, 4);
    pad_kernel<<<pg, pb, 0, stream>>>(x, xp);
    conv_gemm<<<784 * 2, 256, 0, stream>>>(wq, xp, alpha, out);
}

// Round 4
// 369.118 us; speedup vs baseline: 1.1028x; 1.1028x over previous
//
#include <hip/hip_runtime.h>
#include <hip/hip_bf16.h>

typedef unsigned short u16;
typedef __bf16 bf16x8 __attribute__((ext_vector_type(8)));
typedef float f32x4 __attribute__((ext_vector_type(4)));
typedef u16 u16x8 __attribute__((ext_vector_type(8)));

__device__ __forceinline__ u16 f2bf(float f) {
    __bf16 h = (__bf16)f;                 // RNE
    return __builtin_bit_cast(unsigned short, h);
}

__device__ __forceinline__ void gl_lds16(const u16* g, u16* l) {
    __builtin_amdgcn_global_load_lds(
        (const __attribute__((address_space(1))) void*)g,
        (__attribute__((address_space(3))) void*)l, 16, 0, 0);
}

// ---------------------------------------------------------------------------
// Kernel 1: ternary quantization. One block per output channel o.
// Emits Wp in the conv's LDS-image layout:
//   Wp[mt][kc36][kseg8][ol128][c8],  k = f*256+ci -> kc=k>>6, ks=(k>>3)&7, c=k&7
// so each K-chunk's A-tile is ONE contiguous 16 KB block (coalesced staging).
// ---------------------------------------------------------------------------
__global__ __launch_bounds__(256) void quant_kernel(
        const float* __restrict__ w, u16* __restrict__ wp,
        float* __restrict__ alpha) {
    int o = blockIdx.x;
    int t = threadIdx.x;          // t == ci
    const float* wo = w + (size_t)o * 2304;
    float v[9];
    double asum = 0.0;
    #pragma unroll
    for (int i = 0; i < 9; ++i) { v[i] = wo[t * 9 + i]; asum += fabs((double)v[i]); }
    #pragma unroll
    for (int off = 32; off > 0; off >>= 1) asum += __shfl_down(asum, off, 64);
    __shared__ double red[4];
    int wv = t >> 6, lane = t & 63;
    if (lane == 0) red[wv] = asum;
    __syncthreads();
    double delta = 0.7 * ((red[0] + red[1] + red[2] + red[3]) / 2304.0);

    int mt = o >> 7, ol = o & 127;
    int ks = (t >> 3) & 7, c = t & 7;
    double msum = 0.0; int cnt = 0;
    #pragma unroll
    for (int i = 0; i < 9; ++i) {
        double f = (double)v[i];
        float tv = 0.f;
        if (f > delta) tv = 1.f;
        else if (f < -delta) tv = -1.f;
        if (tv != 0.f) { msum += fabs(f); cnt++; }
        int kc = i * 4 + (t >> 6);
        wp[((((size_t)mt * 36 + kc) * 8 + ks) * 128 + ol) * 8 + c] = f2bf(tv);
    }
    #pragma unroll
    for (int off = 32; off > 0; off >>= 1) {
        msum += __shfl_down(msum, off, 64);
        cnt  += __shfl_down(cnt,  off, 64);
    }
    __shared__ double red2[4];
    __shared__ int    redc[4];
    if (lane == 0) { red2[wv] = msum; redc[wv] = cnt; }
    __syncthreads();
    if (t == 0) {
        double ms = red2[0] + red2[1] + red2[2] + red2[3];
        int cn = redc[0] + redc[1] + redc[2] + redc[3];
        alpha[o] = (float)(ms / (double)(cn > 0 ? cn : 1));
    }
}

// ---------------------------------------------------------------------------
// Kernel 2a: zero the padded halo of Xp[img][cihi32][58][58][8].
// ---------------------------------------------------------------------------
__global__ __launch_bounds__(256) void border_kernel(u16* __restrict__ xp) {
    int img = blockIdx.x, cihi = blockIdx.y, t = threadIdx.x;
    if (t >= 228) return;
    int hp, wl;
    if (t < 58)       { hp = 0;           wl = t; }
    else if (t < 116) { hp = 57;          wl = t - 58; }
    else if (t < 172) { hp = t - 116 + 1; wl = 0; }
    else              { hp = t - 172 + 1; wl = 57; }
    u16x8 z = {};
    *(u16x8*)(xp + (((size_t)(img * 32 + cihi) * 58 + hp) * 58 + wl) * 8) = z;
}

// ---------------------------------------------------------------------------
// Kernel 2b: pad/transpose interior. x NCHW fp32 -> Xp[img][cihi32][58][58][8].
// Thread = 4 consecutive w (one float4 per channel): 8 loads, each 1 KB
// contiguous across the wave; 4 contiguous u16x8 stores (64 B per thread).
// grid (32 img, 32 cihi, 4), 256 thr; slot = bz*256+t in [0,784).
// ---------------------------------------------------------------------------
__global__ __launch_bounds__(256) void pad_kernel(
        const float* __restrict__ x, u16* __restrict__ xp) {
    int img  = blockIdx.x;
    int cihi = blockIdx.y;
    int slot = blockIdx.z * 256 + threadIdx.x;
    if (slot >= 784) return;
    int p = slot * 4;                 // flat h*56+w, 56%4==0 -> same h
    int h = p / 56, w = p - h * 56;
    const float* xb = x + ((size_t)(img * 256 + cihi * 8)) * 3136 + p;
    f32x4 v[8];
    #pragma unroll
    for (int j = 0; j < 8; ++j) v[j] = *(const f32x4*)(xb + (size_t)j * 3136);
    u16* ob = xp + (((size_t)(img * 32 + cihi) * 58 + (h + 1)) * 58 + (w + 1)) * 8;
    #pragma unroll
    for (int k = 0; k < 4; ++k) {
        u16x8 ov;
        #pragma unroll
        for (int j = 0; j < 8; ++j) ov[j] = f2bf(v[j][k]);
        *(u16x8*)(ob + k * 8) = ov;
    }
}

// ---------------------------------------------------------------------------
// Kernel 3: implicit GEMM, m97 structure. BK=64, single-buffered LDS
// [kseg8][row128][c8] per operand (16 KB each). A chunk image is contiguous
// in Wp -> 4 coalesced 1 KB gl_lds16 per wave; B likewise (NHWC8 rows).
// Per chunk: stage -> barrier -> 32 MFMA + 16 ds_read_b128 per wave -> barrier.
// ---------------------------------------------------------------------------
__global__ __launch_bounds__(256) void conv_gemm(
        const u16* __restrict__ Wp, const u16* __restrict__ Xp,
        const float* __restrict__ alpha, float* __restrict__ out) {
    __shared__ u16 lsA[8 * 128 * 8];   // 16 KB: [kseg][o_row][8ch]
    __shared__ u16 lsB[8 * 128 * 8];   // 16 KB: [kseg][sp_row][8ch]

    // XCD swizzle: bid&7 = xcd owns a contiguous nt range (B-tile L2 reuse).
    int bid = blockIdx.x;
    int xcd = bid & 7, idx = bid >> 3;
    int mt = idx & 1;
    unsigned nt = (unsigned)(xcd * 98 + (idx >> 1));
    int o_base = mt * 128;
    unsigned sp_base = nt * 128u;

    int t = threadIdx.x;
    int lane = t & 63, wave = t >> 6;
    int wm = (wave >> 1) * 64, wn = (wave & 1) * 64;

    // A staging: chunk kc's image = Wp + mt*294912 + kc*8192, 16 KB contiguous
    const u16* aTile = Wp + (size_t)mt * 294912;

    unsigned sp0 = sp_base + (unsigned)lane;
    unsigned sp1 = sp0 + 64u;
    unsigned img0 = sp0 / 3136u, rem0 = sp0 - img0 * 3136u;
    unsigned oh0 = rem0 / 56u,   ow0 = rem0 - oh0 * 56u;
    unsigned img1 = sp1 / 3136u, rem1 = sp1 - img1 * 3136u;
    unsigned oh1 = rem1 / 56u,   ow1 = rem1 - oh1 * 56u;
    const u16* bB0 = Xp + ((size_t)(img0 * 32) * 58 + oh0) * 58 * 8 + ow0 * 8;
    const u16* bB1 = Xp + ((size_t)(img1 * 32) * 58 + oh1) * 58 * 8 + ow1 * 8;

    int s0 = wave * 2, s1 = s0 + 1;
    u16* dB00 = lsB + (s0 * 128) * 8;
    u16* dB01 = lsB + (s0 * 128 + 64) * 8;
    u16* dB10 = lsB + (s1 * 128) * 8;
    u16* dB11 = lsB + (s1 * 128 + 64) * 8;

    f32x4 acc[4][4] = {};
    int row16 = lane & 15, quad = lane >> 4;

    for (int kc = 0; kc < 36; ++kc) {
        int f  = kc >> 2;
        int kh = f / 3, kw = f - kh * 3;
        int ci8 = (kc & 3) * 8;
        unsigned bhw = (unsigned)kh * 464u + (unsigned)kw * 8u;
        unsigned bo0 = (unsigned)(ci8 + s0) * 26912u + bhw;
        unsigned bo1 = (unsigned)(ci8 + s1) * 26912u + bhw;
        const u16* aC = aTile + kc * 8192;

        #pragma unroll
        for (int q = 0; q < 4; ++q) {
            int seg = wave * 4 + q;                  // 16 segs of 512 u16
            gl_lds16(aC + seg * 512 + lane * 8, lsA + seg * 512);
        }
        gl_lds16(bB0 + bo0, dB00);
        gl_lds16(bB1 + bo0, dB01);
        gl_lds16(bB0 + bo1, dB10);
        gl_lds16(bB1 + bo1, dB11);

        __syncthreads();   // drains vmcnt: staged data visible

        #pragma unroll
        for (int kk = 0; kk < 2; ++kk) {
            int ks = kk * 4 + quad;
            bf16x8 af[4], bfr[4];
            #pragma unroll
            for (int i = 0; i < 4; ++i)
                af[i] = *(const bf16x8*)&lsA[(ks * 128 + wm + i * 16 + row16) * 8];
            #pragma unroll
            for (int j = 0; j < 4; ++j)
                bfr[j] = *(const bf16x8*)&lsB[(ks * 128 + wn + j * 16 + row16) * 8];
            #pragma unroll
            for (int i = 0; i < 4; ++i)
                #pragma unroll
                for (int j = 0; j < 4; ++j)
                    acc[i][j] = __builtin_amdgcn_mfma_f32_16x16x32_bf16(
                                    af[i], bfr[j], acc[i][j], 0, 0, 0);
        }

        __syncthreads();   // all reads done before next chunk's staging
    }

    // epilogue: C/D layout col=lane&15 (sp), row=quad*4+reg (o)
    int col = lane & 15;
    float al[4][4];
    #pragma unroll
    for (int i = 0; i < 4; ++i)
        #pragma unroll
        for (int rg = 0; rg < 4; ++rg)
            al[i][rg] = alpha[o_base + wm + i * 16 + quad * 4 + rg];

    #pragma unroll
    for (int j = 0; j < 4; ++j) {
        unsigned sp = sp_base + (unsigned)(wn + j * 16 + col);
        unsigned img = sp / 3136u;
        unsigned spi = sp - img * 3136u;
        float* ob = out + (size_t)img * 256 * 3136 + spi;
        #pragma unroll
        for (int i = 0; i < 4; ++i) {
            int o = o_base + wm + i * 16 + quad * 4;
            #pragma unroll
            for (int rg = 0; rg < 4; ++rg)
                ob[(size_t)(o + rg) * 3136] = acc[i][j][rg] * al[i][rg];
        }
    }
}

// ---------------------------------------------------------------------------
extern "C" void kernel_launch(void* const* d_in, const int* in_sizes, int n_in,
                              void* d_out, int out_size, void* d_ws, size_t ws_size,
                              hipStream_t stream) {
    const float* x = (const float*)d_in[0];
    const float* w = (const float*)d_in[1];
    float* out = (float*)d_out;

    char* ws = (char*)d_ws;
    // xp: 32*32*58*58*8 bf16 = 55,115,776 B
    u16*   xp    = (u16*)ws;
    u16*   wp    = (u16*)(ws + 55115776);           // 2*36*8*128*8 bf16 = 1,179,648 B
    float* alpha = (float*)(ws + 55115776 + 1179648);

    quant_kernel<<<256, 256, 0, stream>>>(w, wp, alpha);
    dim3 bg(32, 32);
    border_kernel<<<bg, 256, 0, stream>>>(xp);
    dim3 pg(32, 32, 4);
    pad_kernel<<<pg, 256, 0, stream>>>(x, xp);
    conv_gemm<<<784 * 2, 256, 0, stream>>>(wp, xp, alpha, out);
}